// Round 12
// baseline (44.581 us; speedup 1.0000x reference)
//
#include <hip/hip_runtime.h>

#define T_DIM 1024
#define B_DIM 4
#define D_DIM 512
#define DQ (D_DIM / 4)                 // 128 float4 per row
#define NROWS (T_DIM * B_DIM)
#define SSTR ((size_t)NROWS * 4 * DQ)  // scale-slab stride in float4 units

// ---------------- Kernel 1: per-(b,t) inverse L2 norm over D ----------------
__global__ __launch_bounds__(256) void norm_kernel(const float* __restrict__ x,
                                                   float* __restrict__ inv) {
    const int wave = threadIdx.x >> 6;
    const int lane = threadIdx.x & 63;
    const int row  = blockIdx.x * 4 + wave;          // grid = NROWS/4 exactly
    const float4* xr = reinterpret_cast<const float4*>(x) + (size_t)row * DQ;
    float4 a = xr[lane];
    float4 c = xr[lane + 64];
    float s2 = a.x*a.x + a.y*a.y + a.z*a.z + a.w*a.w
             + c.x*c.x + c.y*c.y + c.z*c.z + c.w*c.w;
    #pragma unroll
    for (int off = 32; off > 0; off >>= 1) s2 += __shfl_xor(s2, off, 64);
    if (lane == 0) inv[row] = 1.0f / fmaxf(sqrtf(s2), 1e-12f);
}

// ---------------- Kernel 2: scale-segmented, 64KB-contiguous terminal stores
// Block = (scale si, 2 consecutive j, all 4 b) = 8 consecutive n.
// 256 threads = 2 j-groups x 128 q. Each thread: acc[4 b][4 o].
// Store burst at wave end covers out[si][8n][4o][512d] = 64 KB CONTIGUOUS.
__device__ __forceinline__ void fma4(float4& a, float wt, const float4& v) {
    a.x += wt * v.x; a.y += wt * v.y; a.z += wt * v.z; a.w += wt * v.w;
}

template<int S>
__device__ __forceinline__ void seg_scale(const float* __restrict__ x,
                                          const float* __restrict__ inv,
                                          const float* __restrict__ W,
                                          float* __restrict__ out,
                                          int si, int l) {
    // XCD-chunked bijective remap within the 512-block segment:
    // XCD k gets j-pairs [k*64, (k+1)*64)  -> per-XCD read set ~1.3 MB (L2-fit).
    const int g  = (l & 7) * 64 + (l >> 3);
    const int j  = g * 2 + (threadIdx.x >> 7);       // j-group 0/1
    const int q  = threadIdx.x & 127;                // d-quad
    const int lo = max(0, j - S / 2 + 1);
    const int hi = min(j + S / 2, T_DIM - 1);

    const float4* xq = reinterpret_cast<const float4*>(x) + q;

    float4 acc[4][4];                                // [b][o], compile-time idx
    #pragma unroll
    for (int b = 0; b < 4; ++b)
        #pragma unroll
        for (int o = 0; o < 4; ++o) acc[b][o] = make_float4(0.f, 0.f, 0.f, 0.f);

    #pragma unroll
    for (int k = 0; k < S; ++k) {                    // tap k -> row lo+k
        const int t = lo + k;
        if (t <= hi) {                               // uniform predicate
            #pragma unroll
            for (int b = 0; b < 4; ++b) {
                float4 xv = xq[((size_t)b * T_DIM + t) * DQ];
                const float s = inv[b * T_DIM + t];
                xv.x *= s; xv.y *= s; xv.z *= s; xv.w *= s;
                #pragma unroll
                for (int o = 0; o < 4; ++o)
                    fma4(acc[b][o], W[o * S + k], xv);
            }
        }
    }

    // Terminal store burst: block writes one contiguous 64 KB region.
    #pragma unroll
    for (int b = 0; b < 4; ++b) {
        const int n = j * B_DIM + b;                 // reference row order (T, B)
        float4* op = reinterpret_cast<float4*>(out) + (size_t)si * SSTR
                   + (size_t)n * 4 * DQ + q;
        #pragma unroll
        for (int o = 0; o < 4; ++o)
            op[(size_t)o * DQ] = acc[b][o];
    }
}

// Grid = 2048: [0,512) s4 | [512,1024) s8 | [1024,1536) s16 | [1536,2048) s32.
__global__ __launch_bounds__(256) void pool_kernel(const float* __restrict__ x,
                                                   const float* __restrict__ inv,
                                                   const float* __restrict__ W0,
                                                   const float* __restrict__ W1,
                                                   const float* __restrict__ W2,
                                                   const float* __restrict__ W3,
                                                   float* __restrict__ out) {
    const int bid = blockIdx.x;
    if (bid < 512) {
        seg_scale<4 >(x, inv, W0, out, 0, bid);
    } else if (bid < 1024) {
        seg_scale<8 >(x, inv, W1, out, 1, bid - 512);
    } else if (bid < 1536) {
        seg_scale<16>(x, inv, W2, out, 2, bid - 1024);
    } else {
        seg_scale<32>(x, inv, W3, out, 3, bid - 1536);
    }
}

extern "C" void kernel_launch(void* const* d_in, const int* in_sizes, int n_in,
                              void* d_out, int out_size, void* d_ws, size_t ws_size,
                              hipStream_t stream) {
    const float* x  = (const float*)d_in[0];
    const float* W0 = (const float*)d_in[1];
    const float* W1 = (const float*)d_in[2];
    const float* W2 = (const float*)d_in[3];
    const float* W3 = (const float*)d_in[4];
    float* out = (float*)d_out;
    float* inv = (float*)d_ws;   // NROWS floats = 16 KB scratch

    norm_kernel<<<NROWS / 4, 256, 0, stream>>>(x, inv);
    pool_kernel<<<2048, 256, 0, stream>>>(x, inv, W0, W1, W2, W3, out);
}